// Round 2
// baseline (55.062 us; speedup 1.0000x reference)
//
#include <hip/hip_runtime.h>

// ResiduePose: coords[b,l,a,:] = R(q/|q|) · P[a] + (t[b,l] - mean_l t[b])
// B=32, L=65536, f32. Memory-bound. Two kernels:
//   1) partial_sums: 32 blocks/batch produce partial translation sums (float4 loads)
//   2) pose4: per-block mean finalize (L2-hit) + 4 residues/thread, all 16B/lane accesses

#define BB 32
#define LL 65536
#define PB 32                    // partial-sum blocks per batch
#define GROUPS_PER_BATCH (LL / 4)        // 16384 residue-groups (4 residues each)
#define POSE_BLOCKS_PER_BATCH 64         // 16384 / 256

// ---------------- stage 1: per-(batch, block) partial sums of translation ----------------
__global__ __launch_bounds__(256) void partial_sums_kernel(
    const float4* __restrict__ trans4, float* __restrict__ partials) {
    const int b = blockIdx.x / PB;
    const int p = blockIdx.x % PB;
    const float4* base = trans4 + (size_t)b * (LL * 3 / 4);   // 49152 float4 per batch

    float s0 = 0.f, s1 = 0.f, s2 = 0.f;
    constexpr int GROUPS_PER_BLOCK = GROUPS_PER_BATCH / PB;   // 512
    constexpr int ITERS = GROUPS_PER_BLOCK / 256;             // 2
    const int start = p * GROUPS_PER_BLOCK;
#pragma unroll
    for (int it = 0; it < ITERS; ++it) {
        const int h = start + it * 256 + threadIdx.x;         // residue-group index
        const float4 a = base[(size_t)h * 3 + 0];  // t0.xyz, t1.x
        const float4 c = base[(size_t)h * 3 + 1];  // t1.yz, t2.xy
        const float4 d = base[(size_t)h * 3 + 2];  // t2.z, t3.xyz
        s0 += a.x + a.w + c.z + d.y;
        s1 += a.y + c.x + c.w + d.z;
        s2 += a.z + c.y + d.x + d.w;
    }
#pragma unroll
    for (int off = 32; off > 0; off >>= 1) {
        s0 += __shfl_down(s0, off);
        s1 += __shfl_down(s1, off);
        s2 += __shfl_down(s2, off);
    }
    __shared__ float red[4][3];
    const int wave = threadIdx.x >> 6;
    if ((threadIdx.x & 63) == 0) {
        red[wave][0] = s0; red[wave][1] = s1; red[wave][2] = s2;
    }
    __syncthreads();
    if (threadIdx.x == 0) {
        float a0 = 0.f, a1 = 0.f, a2 = 0.f;
#pragma unroll
        for (int w = 0; w < 4; ++w) { a0 += red[w][0]; a1 += red[w][1]; a2 += red[w][2]; }
        float* dst = partials + ((size_t)b * PB + p) * 3;
        dst[0] = a0; dst[1] = a1; dst[2] = a2;
    }
}

// ---------------- stage 2: fused mean-finalize + pose, 4 residues/thread ----------------
__global__ __launch_bounds__(256) void pose4_kernel(
    const float4* __restrict__ trans4, const float4* __restrict__ quat4,
    const float* __restrict__ partials, float4* __restrict__ out4) {
    const int b = blockIdx.x >> 6;          // 64 blocks per batch
    const int blk = blockIdx.x & 63;

    __shared__ float mean[3];
    if (threadIdx.x < 3) {
        float s = 0.f;
#pragma unroll
        for (int p = 0; p < PB; ++p) s += partials[((size_t)b * PB + p) * 3 + threadIdx.x];
        mean[threadIdx.x] = s * (1.0f / (float)LL);
    }
    __syncthreads();
    const float mx = mean[0], my = mean[1], mz = mean[2];

    // residue-group index (4 residues per group)
    const size_t g = (size_t)b * GROUPS_PER_BATCH + blk * 256 + threadIdx.x;

    const float4 ta = trans4[g * 3 + 0];    // t0.xyz t1.x
    const float4 tb = trans4[g * 3 + 1];    // t1.yz  t2.xy
    const float4 tc = trans4[g * 3 + 2];    // t2.z   t3.xyz

    float4 q[4];
    q[0] = quat4[g * 4 + 0];
    q[1] = quat4[g * 4 + 1];
    q[2] = quat4[g * 4 + 2];
    q[3] = quat4[g * 4 + 3];

    const float tx[4] = { ta.x - mx, ta.w - mx, tb.z - mx, tc.y - mx };
    const float ty[4] = { ta.y - my, tb.x - my, tb.w - my, tc.z - my };
    const float tz[4] = { ta.z - mz, tb.y - mz, tc.x - mz, tc.w - mz };

    // idealized internal coords (N, CA=origin, C, CB)
    const float Nx = 1.460091f;
    const float Cx = -0.56431316f, Cy = 1.41695817f;
    const float Bx = -0.52426314f, By = -0.76611338f, Bz = 1.20561194f;

#pragma unroll
    for (int u = 0; u < 4; ++u) {
        float r = q[u].x, i = q[u].y, j = q[u].z, k = q[u].w;
        const float inv = 1.0f / (sqrtf(r * r + i * i + j * j + k * k) + 1e-6f);
        r *= inv; i *= inv; j *= inv; k *= inv;

        const float R00 = 1.f - 2.f * (j * j + k * k);
        const float R01 = 2.f * (i * j - k * r);
        const float R02 = 2.f * (i * k + j * r);
        const float R10 = 2.f * (i * j + k * r);
        const float R11 = 1.f - 2.f * (i * i + k * k);
        const float R12 = 2.f * (j * k - i * r);
        const float R20 = 2.f * (i * k - j * r);
        const float R21 = 2.f * (j * k + i * r);
        const float R22 = 1.f - 2.f * (i * i + j * j);

        const float N0 = R00 * Nx + tx[u], N1 = R10 * Nx + ty[u], N2 = R20 * Nx + tz[u];
        const float C0 = R00 * Cx + R01 * Cy + tx[u];
        const float C1 = R10 * Cx + R11 * Cy + ty[u];
        const float C2 = R20 * Cx + R21 * Cy + tz[u];
        const float B0 = R00 * Bx + R01 * By + R02 * Bz + tx[u];
        const float B1 = R10 * Bx + R11 * By + R12 * Bz + ty[u];
        const float B2 = R20 * Bx + R21 * By + R22 * Bz + tz[u];

        // per residue: N(3) CA(3) C(3) CB(3) = 12 floats = 3 float4
        const size_t o = g * 12 + (size_t)u * 3;
        out4[o + 0] = make_float4(N0, N1, N2, tx[u]);
        out4[o + 1] = make_float4(ty[u], tz[u], C0, C1);
        out4[o + 2] = make_float4(C2, B0, B1, B2);
    }
}

extern "C" void kernel_launch(void* const* d_in, const int* in_sizes, int n_in,
                              void* d_out, int out_size, void* d_ws, size_t ws_size,
                              hipStream_t stream) {
    const float4* trans4 = (const float4*)d_in[0];     // (B,L,3) f32
    const float4* quat4 = (const float4*)d_in[1];      // (B,L,4) f32
    float4* out4 = (float4*)d_out;                     // (B,L,4,3) f32

    float* partials = (float*)d_ws;                    // B*PB*3 floats

    partial_sums_kernel<<<BB * PB, 256, 0, stream>>>(trans4, partials);
    pose4_kernel<<<BB * POSE_BLOCKS_PER_BATCH, 256, 0, stream>>>(trans4, quat4, partials, out4);
}

// Round 3
// 34.110 us; speedup vs baseline: 1.6143x; 1.6143x over previous
//
#include <hip/hip_runtime.h>

// ResiduePose: coords[b,l,a,:] = R(q/|q|) · P[a] + (t[b,l] - mean_l t[b])
// B=32, L=65536, f32. Memory-bound.
//   stage 1: per-(batch,block) partial translation sums, float4 loads
//   stage 2: fused mean-finalize + pose. 1 residue/thread (quat loads perfectly
//            coalesced), trans staged through LDS (coalesced float4 in, free
//            stride-3 scalar out), output staged through LDS so all global
//            stores are lane-contiguous float4.

#define BB 32
#define LL 65536
#define PB 32                            // partial-sum blocks per batch
#define RES_PER_BLOCK 256
#define POSE_BLOCKS ((BB * LL) / RES_PER_BLOCK)   // 8192

// ---------------- stage 1: per-(batch, block) partial sums of translation ----------------
__global__ __launch_bounds__(256) void partial_sums_kernel(
    const float4* __restrict__ trans4, float* __restrict__ partials) {
    const int b = blockIdx.x / PB;
    const int p = blockIdx.x % PB;
    const float4* base = trans4 + (size_t)b * (LL * 3 / 4);   // 49152 float4 per batch

    float s0 = 0.f, s1 = 0.f, s2 = 0.f;
    constexpr int GROUPS_PER_BATCH = LL / 4;                  // 16384
    constexpr int GROUPS_PER_BLOCK = GROUPS_PER_BATCH / PB;   // 512
    constexpr int ITERS = GROUPS_PER_BLOCK / 256;             // 2
    const int start = p * GROUPS_PER_BLOCK;
#pragma unroll
    for (int it = 0; it < ITERS; ++it) {
        const int h = start + it * 256 + threadIdx.x;
        const float4 a = base[(size_t)h * 3 + 0];  // t0.xyz, t1.x
        const float4 c = base[(size_t)h * 3 + 1];  // t1.yz, t2.xy
        const float4 d = base[(size_t)h * 3 + 2];  // t2.z, t3.xyz
        s0 += a.x + a.w + c.z + d.y;
        s1 += a.y + c.x + c.w + d.z;
        s2 += a.z + c.y + d.x + d.w;
    }
#pragma unroll
    for (int off = 32; off > 0; off >>= 1) {
        s0 += __shfl_down(s0, off);
        s1 += __shfl_down(s1, off);
        s2 += __shfl_down(s2, off);
    }
    __shared__ float red[4][3];
    const int wave = threadIdx.x >> 6;
    if ((threadIdx.x & 63) == 0) {
        red[wave][0] = s0; red[wave][1] = s1; red[wave][2] = s2;
    }
    __syncthreads();
    if (threadIdx.x == 0) {
        float a0 = 0.f, a1 = 0.f, a2 = 0.f;
#pragma unroll
        for (int w = 0; w < 4; ++w) { a0 += red[w][0]; a1 += red[w][1]; a2 += red[w][2]; }
        float* dst = partials + ((size_t)b * PB + p) * 3;
        dst[0] = a0; dst[1] = a1; dst[2] = a2;
    }
}

// ---------------- stage 2: fused mean + pose, LDS-staged I/O ----------------
__global__ __launch_bounds__(256) void pose_kernel(
    const float4* __restrict__ trans4, const float4* __restrict__ quat4,
    const float* __restrict__ partials, float4* __restrict__ out4) {
    __shared__ float4 stage[768];   // 12 KB: trans staging, then output staging
    __shared__ float mean[3];

    const int tid = threadIdx.x;
    const int b = blockIdx.x >> 8;                      // 256 pose-blocks per batch
    const size_t r0 = (size_t)blockIdx.x * RES_PER_BLOCK;

    // Phase A: coalesced trans staging (192 float4 = 256 residues x 3 floats),
    // while 3 spare threads finalize this batch's mean from the 96 partials (L2-hit).
    if (tid < 192) {
        stage[tid] = trans4[r0 * 3 / 4 + tid];
    } else if (tid >= 253) {
        const int c = tid - 253;                        // component 0..2
        float s = 0.f;
#pragma unroll
        for (int p = 0; p < PB; ++p) s += partials[((size_t)b * PB + p) * 3 + c];
        mean[c] = s * (1.0f / (float)LL);
    }
    __syncthreads();

    const float mx = mean[0], my = mean[1], mz = mean[2];
    const float* sf = (const float*)stage;              // stride-3 scalar reads: 2-way, free
    const float tx = sf[tid * 3 + 0] - mx;
    const float ty = sf[tid * 3 + 1] - my;
    const float tz = sf[tid * 3 + 2] - mz;

    const float4 q4 = quat4[r0 + tid];                  // perfect 16B/lane coalescing
    float r = q4.x, i = q4.y, j = q4.z, k = q4.w;
    const float inv = 1.0f / (sqrtf(r * r + i * i + j * j + k * k) + 1e-6f);
    r *= inv; i *= inv; j *= inv; k *= inv;

    const float R00 = 1.f - 2.f * (j * j + k * k);
    const float R01 = 2.f * (i * j - k * r);
    const float R02 = 2.f * (i * k + j * r);
    const float R10 = 2.f * (i * j + k * r);
    const float R11 = 1.f - 2.f * (i * i + k * k);
    const float R12 = 2.f * (j * k - i * r);
    const float R20 = 2.f * (i * k - j * r);
    const float R21 = 2.f * (j * k + i * r);
    const float R22 = 1.f - 2.f * (i * i + j * j);

    // idealized internal coords (N, CA=origin, C, CB)
    const float Nx = 1.460091f;
    const float Cx = -0.56431316f, Cy = 1.41695817f;
    const float Bx = -0.52426314f, By = -0.76611338f, Bz = 1.20561194f;

    const float N0 = R00 * Nx + tx, N1 = R10 * Nx + ty, N2 = R20 * Nx + tz;
    const float C0 = R00 * Cx + R01 * Cy + tx;
    const float C1 = R10 * Cx + R11 * Cy + ty;
    const float C2 = R20 * Cx + R21 * Cy + tz;
    const float B0 = R00 * Bx + R01 * By + R02 * Bz + tx;
    const float B1 = R10 * Bx + R11 * By + R12 * Bz + ty;
    const float B2 = R20 * Bx + R21 * By + R22 * Bz + tz;

    // Phase B: stage the 12 output floats in LDS (b128 writes, phase-disjoint banks)
    __syncthreads();   // done reading trans staging
    stage[tid * 3 + 0] = make_float4(N0, N1, N2, tx);
    stage[tid * 3 + 1] = make_float4(ty, tz, C0, C1);
    stage[tid * 3 + 2] = make_float4(C2, B0, B1, B2);
    __syncthreads();

    // Phase C: 3 perfectly lane-contiguous float4 stores per thread
    const size_t ob = r0 * 3;                           // block's first output float4
    out4[ob + 0 * 256 + tid] = stage[0 * 256 + tid];
    out4[ob + 1 * 256 + tid] = stage[1 * 256 + tid];
    out4[ob + 2 * 256 + tid] = stage[2 * 256 + tid];
}

extern "C" void kernel_launch(void* const* d_in, const int* in_sizes, int n_in,
                              void* d_out, int out_size, void* d_ws, size_t ws_size,
                              hipStream_t stream) {
    const float4* trans4 = (const float4*)d_in[0];     // (B,L,3) f32
    const float4* quat4 = (const float4*)d_in[1];      // (B,L,4) f32
    float4* out4 = (float4*)d_out;                     // (B,L,4,3) f32

    float* partials = (float*)d_ws;                    // B*PB*3 floats

    partial_sums_kernel<<<BB * PB, 256, 0, stream>>>(trans4, partials);
    pose_kernel<<<POSE_BLOCKS, 256, 0, stream>>>(trans4, quat4, partials, out4);
}